// Round 7
// baseline (1061.467 us; speedup 1.0000x reference)
//
#include <hip/hip_runtime.h>
#include <stdint.h>

// ---------------- problem constants ----------------
constexpr int kB  = 4;
constexpr int kT  = 4096;
constexpr int kC  = 1024;
constexpr int kH  = 16;
constexpr int kN  = 64;     // head size
constexpr int kQ  = 256;    // chunk length
constexpr int kNC = 16;     // chunks (T/Q)
constexpr int kBT = kB * kT;

typedef unsigned short u16;
typedef short  s16x8 __attribute__((ext_vector_type(8)));
typedef float  f32x4 __attribute__((ext_vector_type(4)));
typedef unsigned int __attribute__((address_space(1))) u32_as1;
typedef unsigned int __attribute__((address_space(3))) u32_as3;

struct U16x4 { u16 a, b, c, d; } __attribute__((aligned(8)));

__device__ __forceinline__ float bf2f(u16 h) {
  union { unsigned int u; float f; } v; v.u = ((unsigned int)h) << 16; return v.f;
}
__device__ __forceinline__ u16 f2bf(float f) {
  union { float f; unsigned int u; } v; v.f = f;
  unsigned int r = (v.u + 0x7FFFu + ((v.u >> 16) & 1u)) >> 16;
  return (u16)r;
}
__device__ __forceinline__ f32x4 mfma16(s16x8 a, s16x8 b, f32x4 c) {
  return __builtin_amdgcn_mfma_f32_16x16x32_bf16(a, b, c, 0, 0, 0);
}
// async global->LDS, 16B per lane. LDS dest = wave-uniform base + lane*16.
__device__ __forceinline__ void gld16(const void* g, void* l) {
  __builtin_amdgcn_global_load_lds((const u32_as1*)g, (u32_as3*)l, 16, 0, 0);
}

// ---------------- weight f32 -> bf16 ----------------
struct WPtrs { const float* src[12]; };

__global__ __launch_bounds__(256)
void wconv_kernel(WPtrs p, u16* __restrict__ dst) {
  int chunk = blockIdx.y;
  const float* s = p.src[chunk];
  u16* d = dst + (size_t)chunk * (kC * kC);
  int idx = (blockIdx.x * 256 + threadIdx.x) * 4;
  float4 v = *(const float4*)&s[idx];
  U16x4 o = { f2bf(v.x), f2bf(v.y), f2bf(v.z), f2bf(v.w) };
  *(U16x4*)&d[idx] = o;
}

// ---------------- LayerNorm + time-shift mix (1..4 outputs, one pass) ----------------
template<int NOUT>
__global__ __launch_bounds__(256)
void ln_mix_kernel(const float* __restrict__ x,
                   const float* __restrict__ lw, const float* __restrict__ lb,
                   const float* __restrict__ m0p, const float* __restrict__ m1p,
                   const float* __restrict__ m2p, const float* __restrict__ m3p,
                   u16* __restrict__ o0, u16* __restrict__ o1,
                   u16* __restrict__ o2, u16* __restrict__ o3)
{
  int row = blockIdx.x;
  int t = row & (kT - 1);
  int tid = threadIdx.x;
  int c0 = tid * 4;
  float4 xc = *(const float4*)&x[(size_t)row * kC + c0];
  float4 xp; xp.x = 0.f; xp.y = 0.f; xp.z = 0.f; xp.w = 0.f;
  bool hasprev = (t != 0);
  if (hasprev) xp = *(const float4*)&x[(size_t)(row - 1) * kC + c0];

  float s0 = xc.x + xc.y + xc.z + xc.w;
  float q0 = xc.x*xc.x + xc.y*xc.y + xc.z*xc.z + xc.w*xc.w;
  float s1 = xp.x + xp.y + xp.z + xp.w;
  float q1 = xp.x*xp.x + xp.y*xp.y + xp.z*xp.z + xp.w*xp.w;
  #pragma unroll
  for (int off = 1; off < 64; off <<= 1) {
    s0 += __shfl_xor(s0, off); q0 += __shfl_xor(q0, off);
    s1 += __shfl_xor(s1, off); q1 += __shfl_xor(q1, off);
  }
  __shared__ float red[16];
  int wid = tid >> 6, lane = tid & 63;
  if (lane == 0) { red[wid*4+0]=s0; red[wid*4+1]=q0; red[wid*4+2]=s1; red[wid*4+3]=q1; }
  __syncthreads();
  s0 = red[0]+red[4]+red[8]+red[12];
  q0 = red[1]+red[5]+red[9]+red[13];
  s1 = red[2]+red[6]+red[10]+red[14];
  q1 = red[3]+red[7]+red[11]+red[15];
  float mu0 = s0 * (1.f/kC), v0 = q0*(1.f/kC) - mu0*mu0, rs0 = rsqrtf(v0 + 1e-5f);
  float mu1 = s1 * (1.f/kC), v1 = q1*(1.f/kC) - mu1*mu1, rs1 = rsqrtf(v1 + 1e-5f);

  float cx[4] = { xc.x, xc.y, xc.z, xc.w };
  float px[4] = { xp.x, xp.y, xp.z, xp.w };
  U16x4 w0, w1, w2, w3;
  u16* p0 = (u16*)&w0; u16* p1 = (u16*)&w1; u16* p2 = (u16*)&w2; u16* p3 = (u16*)&w3;
  #pragma unroll
  for (int j = 0; j < 4; ++j) {
    int c = c0 + j;
    float lwc = lw[c], lbc = lb[c];
    float lnc = (cx[j] - mu0) * rs0 * lwc + lbc;
    float lnp = hasprev ? (px[j] - mu1) * rs1 * lwc + lbc : 0.f;
    float d = lnp - lnc;
    p0[j] = f2bf(lnc + d * m0p[c]);
    if (NOUT >= 2) p1[j] = f2bf(lnc + d * m1p[c]);
    if (NOUT >= 4) { p2[j] = f2bf(lnc + d * m2p[c]); p3[j] = f2bf(lnc + d * m3p[c]); }
  }
  size_t ob = (size_t)row * kC + c0;
  *(U16x4*)&o0[ob] = w0;
  if (NOUT >= 2) *(U16x4*)&o1[ob] = w1;
  if (NOUT >= 4) { *(U16x4*)&o2[ob] = w2; *(U16x4*)&o3[ob] = w3; }
}

// ---------------- 256x256 MFMA GEMM: C[M,N] = A[M,K] @ W[N,K]^T ----------------
// 512 threads = 8 waves. LDS 128 KB (2 dbuf x (A 256x64 + B 256x64) bf16,
// row-halved, chunk^=(row&7) XOR swizzle). ONE vmcnt(0)+s_barrier per K-tile:
// per-wave vmcnt(0) + collective barrier certifies the whole tile (each wave
// staged its own rows and drained them); mid-tile barriers removed so the
// compiler pipelines the 24-ds_read/64-MFMA tile body and waves drift to
// overlap pipes (m114). Stage all 4 halves of t+1 right after the barrier ->
// a full tile (~2500cy) of flight time before the next drain.
enum { EPI_BF16 = 0, EPI_RESID = 1, EPI_RELU2 = 2, EPI_SIGMOID = 3,
       EPI_FINAL0 = 4, EPI_FINALACC = 5 };

#define LOAD_A(mh, bfv)                                                       \
  _Pragma("unroll") for (int mf = 0; mf < 4; ++mf)                            \
    _Pragma("unroll") for (int ks = 0; ks < 2; ++ks)                          \
      Ar[mf][ks] = *(const s16x8*)&As[bfv][mh][                               \
          (wm2*64 + mf*16 + lo)*64 + 8*((ks*4 + q) ^ (lo & 7))];

#define LOAD_B(dst, nh, bfv)                                                  \
  _Pragma("unroll") for (int nf = 0; nf < 2; ++nf)                            \
    _Pragma("unroll") for (int ks = 0; ks < 2; ++ks)                          \
      dst[nf][ks] = *(const s16x8*)&Bs[bfv][nh][                              \
          (wn2*32 + nf*16 + lo)*64 + 8*((ks*4 + q) ^ (lo & 7))];

#define MFMA_Q(p, Bsrc)                                                       \
  __builtin_amdgcn_s_setprio(1);                                              \
  _Pragma("unroll") for (int mf = 0; mf < 4; ++mf)                            \
    _Pragma("unroll") for (int nf = 0; nf < 2; ++nf)                          \
      _Pragma("unroll") for (int ks = 0; ks < 2; ++ks)                        \
        acc[p][mf][nf] = mfma16(Ar[mf][ks], Bsrc[nf][ks], acc[p][mf][nf]);    \
  __builtin_amdgcn_s_setprio(0);

#define GWAIT(n) asm volatile("s_waitcnt vmcnt(" #n ")" ::: "memory")

template<int EPI, int LDB, int KDIM = 1024, int LDC = 1024>
__global__ __launch_bounds__(512, 2)
void gemm256(const u16* __restrict__ A, const u16* __restrict__ Wt,
             void* __restrict__ out, const float* __restrict__ resid,
             const u16* __restrict__ sigb)
{
  constexpr int NT = KDIM / 64;
  __shared__ u16 As[2][2][128 * 64];   // [dbuf][row-half][128 rows][64 k] swizzled
  __shared__ u16 Bs[2][2][128 * 64];

  const int tid = threadIdx.x;
  const int w = tid >> 6, lane = tid & 63;
  const int lo = lane & 15, q = lane >> 4;
  const int wm2 = w >> 2, wn2 = w & 3;      // 2x4 wave grid within a quadrant

  // XCD-chunked bijective swizzle (nwg % 8 == 0 for all launches here)
  const int nwg = gridDim.x * gridDim.y;
  const int orig = blockIdx.y * gridDim.x + blockIdx.x;
  const int cpx = nwg >> 3;
  const int wg = (orig & 7) * cpx + (orig >> 3);
  const int n0 = (wg % gridDim.x) * 256;
  const int m0 = (wg / gridDim.x) * 256;

  // staging geometry: per gld16, wave w covers 8 rows x 128B; lane -> (row
  // srow=lane>>3, chunk d=lane&7); source chunk pre-swizzled d ^ (row&7).
  const int srow = lane >> 3;
  const int sch  = (lane & 7) ^ srow;       // row&7 == srow (w*8, 64 are mult of 8)

  const u16* Ag = A  + (size_t)m0 * KDIM;   // A row stride == KDIM
  const u16* Bg = Wt + (size_t)n0 * LDB;

  f32x4 acc[4][4][2] = {};                  // [quadrant][mf][nf]

  auto stageA = [&](int bf, int kt, int h) {
    const u16* src = Ag + (size_t)(h*128 + w*8 + srow) * KDIM + kt*64 + 8*sch;
    u16* dst = &As[bf][h][(w*8) * 64];
    gld16(src, dst);
    gld16(src + (size_t)64 * KDIM, dst + 64*64);
  };
  auto stageB = [&](int bf, int kt, int h) {
    const u16* src = Bg + (size_t)(h*128 + w*8 + srow) * LDB + kt*64 + 8*sch;
    u16* dst = &Bs[bf][h][(w*8) * 64];
    gld16(src, dst);
    gld16(src + (size_t)64 * LDB, dst + 64*64);
  };

  // prologue: stage tile 0 into buf0 -> 8 loads in flight
  stageA(0, 0, 0); stageB(0, 0, 0); stageB(0, 0, 1); stageA(0, 0, 1);

  s16x8 Ar[4][2];                  // current A row-half frags
  s16x8 Br0[2][2], Br1[2][2];      // B col-half 0 / 1 frags (live whole K-tile)

  for (int t = 0; t < NT; ++t) {
    int bf = t & 1, nb = bf ^ 1;
    GWAIT(0);                        // certify own stage-loads of tile t
    __builtin_amdgcn_s_barrier();    // collective: tile t in LDS; nb free
    if (t + 1 < NT) {                // stage all of tile t+1 up front
      stageA(nb, t + 1, 0); stageB(nb, t + 1, 0);
      stageB(nb, t + 1, 1); stageA(nb, t + 1, 1);
    }
    LOAD_A(0, bf) LOAD_B(Br0, 0, bf)
    MFMA_Q(0, Br0)                   // quadrant (0,0)
    LOAD_B(Br1, 1, bf)
    MFMA_Q(1, Br1)                   // quadrant (0,1)
    LOAD_A(1, bf)
    MFMA_Q(2, Br1)                   // quadrant (1,1), reuse Br1
    MFMA_Q(3, Br0)                   // quadrant (1,0), reuse Ar + Br0
  }

  // ---- epilogue ----
  constexpr int MHq[4] = {0, 0, 1, 1}, NHq[4] = {0, 1, 1, 0};
  #pragma unroll
  for (int p = 0; p < 4; ++p) {
    #pragma unroll
    for (int mf = 0; mf < 4; ++mf) {
      #pragma unroll
      for (int nf = 0; nf < 2; ++nf) {
        #pragma unroll
        for (int rg = 0; rg < 4; ++rg) {
          int row = m0 + MHq[p]*128 + wm2*64 + mf*16 + q*4 + rg;
          int col = n0 + NHq[p]*128 + wn2*32 + nf*16 + lo;
          size_t idx = (size_t)row * LDC + col;
          float v = acc[p][mf][nf][rg];
          if (EPI == EPI_BF16) {
            ((u16*)out)[idx] = f2bf(v);
          } else if (EPI == EPI_RESID) {
            ((float*)out)[idx] = resid[idx] + v;
          } else if (EPI == EPI_RELU2) {
            float tv = v > 0.f ? v : 0.f;
            ((u16*)out)[idx] = f2bf(tv * tv);
          } else if (EPI == EPI_SIGMOID) {
            ((u16*)out)[idx] = f2bf(1.f / (1.f + __expf(-v)));
          } else if (EPI == EPI_FINAL0) {
            float s = bf2f(sigb[idx]);
            ((float*)out)[idx] = resid[idx] + s * v;
          } else { // EPI_FINALACC
            float s = bf2f(sigb[idx]);
            ((float*)out)[idx] += s * v;
          }
        }
      }
    }
  }
}

// ---------------- transpose (B,T,H,N)->(B,H,N,T), optional decay fold ----------------
template<bool DECAY>
__global__ __launch_bounds__(256)
void transpose_nt(const u16* __restrict__ src, const float* __restrict__ decay,
                  u16* __restrict__ dst)
{
  __shared__ u16 tile[64][72];
  int t0 = blockIdx.x * 64;
  int h  = blockIdx.y;
  int b  = blockIdx.z;
  int tid = threadIdx.x;
  int lrow = tid >> 3;           // 0..31
  int lcol = (tid & 7) * 8;      // 0..56
  float ed = DECAY ? __expf(decay[h]) : 0.f;

  #pragma unroll
  for (int rr = 0; rr < 2; ++rr) {
    int tr = lrow + rr * 32;
    *(uint4*)&tile[tr][lcol] =
        *(const uint4*)&src[((size_t)(b*kT + t0 + tr)) * kC + h*64 + lcol];
  }
  __syncthreads();
  #pragma unroll
  for (int rr = 0; rr < 2; ++rr) {
    int n = lrow + rr * 32;
    u16 o[8] __attribute__((aligned(16)));
    #pragma unroll
    for (int j = 0; j < 8; ++j) {
      int tglob = t0 + lcol + j;
      float v = bf2f(tile[lcol + j][n]);
      if (DECAY) v *= __expf(-ed * (float)(kQ - 1 - (tglob & (kQ - 1))));
      o[j] = f2bf(v);
    }
    *(uint4*)&dst[((size_t)((b*kH + h)*64 + n)) * kT + t0 + lcol] = *(uint4*)o;
  }
}

// ---------------- per-chunk partial state (parallel over all (b,h,c)) ----------------
__global__ __launch_bounds__(256)
void schunk_kernel(const u16* __restrict__ kTw, const u16* __restrict__ vT,
                   u16* __restrict__ SinitT)
{
  __shared__ u16 kls[64 * 136];   // 17408 B, pitch 136 (272B, 16B-aligned)
  __shared__ u16 vls[64 * 136];
  int blk = blockIdx.x;
  int c = blk & (kNC - 1), bh = blk >> 4;
  int tid = threadIdx.x, w = tid >> 6, lane = tid & 63;
  int lo = lane & 15, q = lane >> 4;
  const u16* kg = kTw + (size_t)bh * 64 * kT;
  const u16* vg = vT  + (size_t)bh * 64 * kT;
  f32x4 acc[4] = {};
  for (int half = 0; half < 2; ++half) {
    __syncthreads();
    #pragma unroll
    for (int it = 0; it < 4; ++it) {
      int row = it*16 + (tid >> 4);
      int c8  = (tid & 15) * 8;
      size_t gcol = (size_t)c * kQ + half*128 + c8;
      *(uint4*)&kls[row*136 + c8] = *(const uint4*)&kg[(size_t)row * kT + gcol];
      *(uint4*)&vls[row*136 + c8] = *(const uint4*)&vg[(size_t)row * kT + gcol];
    }
    __syncthreads();
    #pragma unroll
    for (int ks = 0; ks < 4; ++ks) {
      s16x8 av = *(const s16x8*)&vls[(w*16 + lo)*136 + ks*32 + q*8];
      #pragma unroll
      for (int nt = 0; nt < 4; ++nt) {
        s16x8 bv = *(const s16x8*)&kls[(nt*16 + lo)*136 + ks*32 + q*8];
        acc[nt] = mfma16(av, bv, acc[nt]);
      }
    }
  }
  u16* ob = SinitT + ((size_t)bh * kNC + c) * 4096;
  #pragma unroll
  for (int nt = 0; nt < 4; ++nt)
    #pragma unroll
    for (int rg = 0; rg < 4; ++rg)
      ob[(w*16 + q*4 + rg) * 64 + nt*16 + lo] = f2bf(acc[nt][rg]);
}

// decay prefix over chunk partials, in place (read slot c before overwriting).
__global__ __launch_bounds__(256)
void sscan_kernel(const float* __restrict__ decay, u16* __restrict__ SinitT)
{
  int bh = blockIdx.x;
  int h = bh & (kH - 1);
  float wQ = __expf(-__expf(decay[h]) * (float)kQ);
  u16* base = SinitT + ((size_t)bh * kNC) * 4096 + threadIdx.x * 16;
  float S[16];
  #pragma unroll
  for (int i = 0; i < 16; ++i) S[i] = 0.f;
  for (int c = 0; c < kNC; ++c) {
    u16* p = base + (size_t)c * 4096;
    u16 tmp[16] __attribute__((aligned(16)));
    *(uint4*)&tmp[0] = *(const uint4*)p;
    *(uint4*)&tmp[8] = *(const uint4*)(p + 8);
    u16 outv[16] __attribute__((aligned(16)));
    #pragma unroll
    for (int i = 0; i < 16; ++i) {
      outv[i] = f2bf(S[i]);
      S[i] = wQ * S[i] + bf2f(tmp[i]);
    }
    *(uint4*)p = *(uint4*)&outv[0];
    *(uint4*)(p + 8) = *(uint4*)&outv[8];
  }
}

// ---------------- WKV intra-chunk + GroupNorm + silu gate ----------------
__global__ __launch_bounds__(256, 3)
void wkv_y_kernel(const u16* __restrict__ r, const u16* __restrict__ k,
                  const u16* __restrict__ vT, const u16* __restrict__ SinitT,
                  const u16* __restrict__ gpre, const float* __restrict__ decay,
                  const float* __restrict__ faaaa, const float* __restrict__ gnw,
                  const float* __restrict__ gnb, u16* __restrict__ yg)
{
  __shared__ u16 kls[2][64 * 64]; // 8 KB per buf, [64 rows][64 cols] swizzled
  __shared__ u16 vls[2][64 * 64];
  __shared__ u16 pbuf[64 * 72];   // 9216 B: per-wave P strips; reused as GN-store buf
  __shared__ float wpow[kQ];      // 1 KB    (total LDS 42.25 KB)

  int blk = blockIdx.x;
  int chunk = blk & (kNC - 1), bh = blk >> 4;
  int b = bh >> 4, h = bh & (kH - 1);
  int tid = threadIdx.x, w = tid >> 6, lane = tid & 63;
  int lo = lane & 15, q = lane >> 4;
  int t0 = chunk * kQ;
  float ed = __expf(decay[h]);
  wpow[tid] = __expf(-ed * (float)tid);
  float uu = faaaa[h];

  const size_t rbase = ((size_t)(b*kT + t0)) * kC + h*64;

  const int srow = lane >> 3;                   // row within 8-row group, = row&7
  const int scol = 8 * ((lane & 7) ^ srow);     // inverse-swizzled source col (elems)
  const u16* kg0 = k  + ((size_t)(b*kT + t0)) * kC + h*64;  // rows=time, stride kC
  const u16* vg0 = vT + ((size_t)(bh*64)) * kT + t0;        // rows=n,    stride kT

  auto stage = [&](int dstbuf, int jb_) {
    const u16* kgj = kg0 + (size_t)(jb_*64) * kC;
    const u16* vgj = vg0 + jb_*64;
    #pragma unroll
    for (int it = 0; it < 2; ++it) {
      int ci  = it*4 + w;            // 8 chunks of 1 KB per strip
      int row = ci*8 + srow;
      gld16(kgj + (size_t)row * kC + scol, &kls[dstbuf][ci*512]);
      gld16(vgj + (size_t)row * kT + scol, &vls[dstbuf][ci*512]);
    }
  };

  // issue jb=0 staging first: its latency hides under r-frag loads + stateA MFMAs
  stage(0, 0);

  // ---- r A-frags once, direct from global, kept in registers ----
  s16x8 af[4][2];
  #pragma unroll
  for (int mt = 0; mt < 4; ++mt)
    #pragma unroll
    for (int ks = 0; ks < 2; ++ks)
      af[mt][ks] = *(const s16x8*)&r[rbase + (size_t)(mt*64 + w*16 + lo)*kC + ks*32 + q*8];

  f32x4 y[4][4] = {};
  // ---- step A: y = rc @ stateT^T, B-frags direct from global ----
  {
    const u16* Sg = SinitT + (size_t)blk * 4096;
    #pragma unroll
    for (int ks = 0; ks < 2; ++ks) {
      s16x8 bf[4];
      #pragma unroll
      for (int nt = 0; nt < 4; ++nt)
        bf[nt] = *(const s16x8*)&Sg[(nt*16 + lo)*64 + ks*32 + q*8];
      #pragma unroll
      for (int mt = 0; mt < 4; ++mt)
        #pragma unroll
        for (int nt = 0; nt < 4; ++nt)
          y[mt][nt] = mfma16(af[mt][ks], bf[nt], y[mt][nt]);
    }
  }
  __syncthreads();   // wpow visibility + stage(0) complete (vmcnt drained)

  // scale by wb_i = w^i
  #pragma unroll
  for (int mt = 0; mt < 4; ++mt)
    #pragma unroll
    for (int rg = 0; rg < 4; ++rg) {
      float wb = wpow[mt*64 + w*16 + q*4 + rg];
      #pragma unroll
      for (int nt = 0; nt < 4; ++nt) y[mt][nt][rg] *= wb;
    }

  // ---- intra-chunk: j-blocks of 64, double-buffered LDS, 1 barrier per jb ----
  u16* P = &pbuf[(w * 16) * 72];
  int buf = 0;
  #pragma unroll
  for (int jb = 0; jb < 4; ++jb) {
    if (jb < 3) stage(buf ^ 1, jb + 1);      // prefetch next strip-pair
    #pragma unroll
    for (int mt = jb; mt < 4; ++mt) {
      // QK^T: k B-frags from swizzled LDS
      f32x4 a[4] = {};
      #pragma unroll
      for (int ks = 0; ks < 2; ++ks)
        #pragma unroll
        for (int nt = 0; nt < 4; ++nt) {
          s16x8 kf = *(const s16x8*)&kls[buf][(nt*16 + lo)*64 + 8*((ks*4 + q) ^ (lo & 7))];
          a[nt] = mfma16(af[mt][ks], kf, a[nt]);
        }
      // mask -> P (wave-private LDS strip, pitch 72)
      #pragma unroll
      for (int nt = 0; nt < 4; ++nt)
        #pragma unroll
        for (int rg = 0; rg < 4; ++rg) {
          int i = mt*64 + w*16 + q*4 + rg;
          int j = jb*64 + nt*16 + lo;
          int d = i - j;
          float val = (d > 0) ? a[nt][rg] * wpow[d-1] : (d == 0 ? a[nt][rg] * uu : 0.f);
          P[(q*4 + rg)*72 + nt*16 + lo] = f2bf(val);
        }
      // PV: v B-frags from swizzled LDS; P A-frag from wave-private LDS
      #pragma unroll
      for (int ks = 0; ks < 2; ++ks) {
        s16x8 pf = *(const s16x8*)&P[lo*72 + ks*32 + q*8];
        #pragma unroll
        for (int nt = 0; nt < 4; ++nt) {
          s16x8 vf = *(const s16x8*)&vls[buf][(nt*16 + lo)*64 + 8*((ks*4 + q) ^ (lo & 7))];
          y[mt][nt] = mfma16(pf, vf, y[mt][nt]);
        }
      }
    }
    __syncthreads();   // prefetch landed + all waves done with buf
    buf ^= 1;
  }

  // ---- GroupNorm + silu gate, strip by strip through pbuf [64][72] ----
  float gw[4], gb[4];
  #pragma unroll
  for (int nt = 0; nt < 4; ++nt) {
    gw[nt] = gnw[h*64 + nt*16 + lo];
    gb[nt] = gnb[h*64 + nt*16 + lo];
  }
  for (int mt = 0; mt < 4; ++mt) {
    #pragma unroll
    for (int rg = 0; rg < 4; ++rg) {
      float s  = y[mt][0][rg] + y[mt][1][rg] + y[mt][2][rg] + y[mt][3][rg];
      float ss = y[mt][0][rg]*y[mt][0][rg] + y[mt][1][rg]*y[mt][1][rg]
               + y[mt][2][rg]*y[mt][2][rg] + y[mt][3][rg]*y[mt][3][rg];
      #pragma unroll
      for (int off = 1; off < 16; off <<= 1) {
        s  += __shfl_xor(s, off);
        ss += __shfl_xor(ss, off);
      }
      float mu  = s * (1.f/64.f);
      float var = ss * (1.f/64.f) - mu*mu;
      float rstd = rsqrtf(var + 6.4e-4f);   // eps = 1e-5 * 64
      #pragma unroll
      for (int nt = 0; nt < 4; ++nt) {
        float val = (y[mt][nt][rg] - mu) * rstd * gw[nt] + gb[nt];
        pbuf[(w*16 + q*4 + rg)*72 + nt*16 + lo] = f2bf(val);
      }
    }
    __syncthreads();
    #pragma unroll
    for (int it = 0; it < 2; ++it) {
      int lrow = it*32 + (tid >> 3);
      int c8  = (tid & 7) * 8;
      size_t ga = rbase + (size_t)(mt*64 + lrow)*kC + c8;
      uint2 ylo = *(const uint2*)&pbuf[lrow*72 + c8];
      uint2 yhi = *(const uint2*)&pbuf[lrow*72 + c8 + 4];
      uint4 gv = *(const uint4*)&gpre[ga];
      u16 yv[8] __attribute__((aligned(16)));
      const u16* ys = (const u16*)&ylo;
      const u16* gs = (const u16*)&gv;
      #pragma unroll
      for (int j = 0; j < 8; ++j) {
        u16 yj = (j < 4) ? ys[j] : ((const u16*)&yhi)[j-4];
        float g = bf2f(gs[j]);
        float sil = g / (1.f + __expf(-g));
        yv[j] = f2bf(bf2f(yj) * sil);
      }
      *(uint4*)&yg[ga] = *(uint4*)yv;
    }
    __syncthreads();
  }
}

// ---------------- launcher ----------------
extern "C" void kernel_launch(void* const* d_in, const int* in_sizes, int n_in,
                              void* d_out, int out_size, void* d_ws, size_t ws_size,
                              hipStream_t stream) {
  const size_t MB = 1024ull * 1024ull;
  if (ws_size < 192 * MB) return;   // graceful diagnostic fail (no OOB)

  const float* x     = (const float*)d_in[0];
  const float* ln1w  = (const float*)d_in[1];
  const float* ln1b  = (const float*)d_in[2];
  const float* tmk   = (const float*)d_in[3];
  const float* tmv   = (const float*)d_in[4];
  const float* tmr   = (const float*)d_in[5];
  const float* tmg   = (const float*)d_in[6];
  const float* decay = (const float*)d_in[7];
  const float* faaaa = (const float*)d_in[8];
  const float* Wr    = (const float*)d_in[9];
  const float* Wk    = (const float*)d_in[10];
  const float* Wv    = (const float*)d_in[11];
  const float* Wg    = (const float*)d_in[12];
  const float* Wo    = (const float*)d_in[13];
  const float* gnw   = (const float*)d_in[14];
  const float* gnb   = (const float*)d_in[15];
  const float* ln2w  = (const float*)d_in[16];
  const float* ln2b  = (const float*)d_in[17];
  const float* cmk   = (const float*)d_in[18];
  const float* cmr   = (const float*)d_in[19];
  const float* Wck   = (const float*)d_in[20];
  const float* Wcv   = (const float*)d_in[21];
  const float* Wcr   = (const float*)d_in[22];

  // lifetime-packed workspace, peak 192 MB. x1 lives in d_out (f32).
  char* ws = (char*)d_ws;
  u16*   Wb     = (u16*)(ws +   0*MB);   // [0,24)   whole run
  u16*   xr     = (u16*)(ws +  24*MB);
  u16*   xk     = (u16*)(ws +  56*MB);
  u16*   xv     = (u16*)(ws +  88*MB);
  u16*   xg     = (u16*)(ws + 120*MB);
  u16*   rb     = (u16*)(ws + 152*MB);
  u16*   kb     = (u16*)(ws +  24*MB);   // after xr dead
  u16*   vb     = (u16*)(ws +  56*MB);   // after xk dead
  u16*   gp     = (u16*)(ws +  88*MB);   // after xv dead
  u16*   vT     = (u16*)(ws + 120*MB);   // after xg dead
  u16*   kTw    = (u16*)(ws +  56*MB);   // after vb dead
  u16*   SinitT = (u16*)(ws + 184*MB);   // 8 MB
  u16*   yg     = (u16*)(ws +  56*MB);   // after kTw dead (post-schunk)
  u16*   xck    = (u16*)(ws +  24*MB);   // after kb dead (post-wkv)
  u16*   xcr    = (u16*)(ws + 152*MB);   // after rb dead (post-wkv)
  u16*   sig    = (u16*)(ws +  56*MB);   // after yg dead (post-resid)
  u16*   hbt    = (u16*)(ws +  88*MB);   // 96 MB [88,184): gp,vT,xcr dead

  const int C2 = kC * kC;
  u16* Wr_b  = Wb + 0*(size_t)C2;
  u16* Wk_b  = Wb + 1*(size_t)C2;
  u16* Wv_b  = Wb + 2*(size_t)C2;
  u16* Wg_b  = Wb + 3*(size_t)C2;
  u16* Wo_b  = Wb + 4*(size_t)C2;
  u16* Wck_b = Wb + 5*(size_t)C2;   // (3072,1024)
  u16* Wcv_b = Wb + 8*(size_t)C2;   // (1024,3072)
  u16* Wcr_b = Wb + 11*(size_t)C2;

  WPtrs wp;
  wp.src[0] = Wr;  wp.src[1] = Wk;  wp.src[2] = Wv;  wp.src[3] = Wg;  wp.src[4] = Wo;
  wp.src[5] = Wck; wp.src[6] = Wck + C2; wp.src[7] = Wck + 2*(size_t)C2;
  wp.src[8] = Wcv; wp.src[9] = Wcv + C2; wp.src[10] = Wcv + 2*(size_t)C2;
  wp.src[11] = Wcr;
  wconv_kernel<<<dim3(C2/1024, 12), 256, 0, stream>>>(wp, Wb);

  // LN1 + 4-way time-shift mix (one pass)
  ln_mix_kernel<4><<<kBT, 256, 0, stream>>>(x, ln1w, ln1b, tmr, tmk, tmv, tmg,
                                            xr, xk, xv, xg);
  // projections: 256^2 GEMM, grid 4 x 64 = 256 blocks (1/CU)
  gemm256<EPI_BF16, kC><<<dim3(4,64), 512, 0, stream>>>(xr, Wr_b, rb, nullptr, nullptr);
  gemm256<EPI_BF16, kC><<<dim3(4,64), 512, 0, stream>>>(xk, Wk_b, kb, nullptr, nullptr);
  gemm256<EPI_BF16, kC><<<dim3(4,64), 512, 0, stream>>>(xv, Wv_b, vb, nullptr, nullptr);
  gemm256<EPI_BF16, kC><<<dim3(4,64), 512, 0, stream>>>(xg, Wg_b, gp, nullptr, nullptr);

  // WKV
  transpose_nt<false><<<dim3(kT/64, kH, kB), 256, 0, stream>>>(vb, decay, vT);
  transpose_nt<true ><<<dim3(kT/64, kH, kB), 256, 0, stream>>>(kb, decay, kTw);
  schunk_kernel<<<kB*kH*kNC, 256, 0, stream>>>(kTw, vT, SinitT);
  sscan_kernel<<<kB*kH, 256, 0, stream>>>(decay, SinitT);
  wkv_y_kernel<<<kB*kH*kNC, 256, 0, stream>>>(rb, kb, vT, SinitT, gp, decay, faaaa,
                                              gnw, gnb, yg);
  // output projection + residual -> d_out (f32 residual stream lives in d_out)
  gemm256<EPI_RESID, kC><<<dim3(4,64), 512, 0, stream>>>(yg, Wo_b, d_out, x, nullptr);

  // channel mix
  ln_mix_kernel<2><<<kBT, 256, 0, stream>>>((const float*)d_out, ln2w, ln2b, cmk, cmr,
                                            nullptr, nullptr, xck, xcr, nullptr, nullptr);
  gemm256<EPI_SIGMOID, kC><<<dim3(4,64), 512, 0, stream>>>(xcr, Wcr_b, sig, nullptr, nullptr);
  // h = relu(xck @ Wck^T)^2, ONE merged N=3072 dispatch (grid 12x64 = 768 wg)
  gemm256<EPI_RELU2, kC, 1024, 3*kC><<<dim3(12,64), 512, 0, stream>>>(
      xck, Wck_b, hbt, nullptr, nullptr);
  // fused final: d_out += sig * (h @ Wcv^T), single K=3072 pass
  gemm256<EPI_FINALACC, 3*kC, 3*kC, kC><<<dim3(4,64), 512, 0, stream>>>(
      hbt, Wcv_b, (float*)d_out, nullptr, sig);
}

// Round 8
// 972.553 us; speedup vs baseline: 1.0914x; 1.0914x over previous
//
#include <hip/hip_runtime.h>
#include <stdint.h>

// ---------------- problem constants ----------------
constexpr int kB  = 4;
constexpr int kT  = 4096;
constexpr int kC  = 1024;
constexpr int kH  = 16;
constexpr int kN  = 64;     // head size
constexpr int kQ  = 256;    // chunk length
constexpr int kNC = 16;     // chunks (T/Q)
constexpr int kBT = kB * kT;

typedef unsigned short u16;
typedef short  s16x8 __attribute__((ext_vector_type(8)));
typedef float  f32x4 __attribute__((ext_vector_type(4)));
typedef unsigned int __attribute__((address_space(1))) u32_as1;
typedef unsigned int __attribute__((address_space(3))) u32_as3;

struct U16x4 { u16 a, b, c, d; } __attribute__((aligned(8)));

__device__ __forceinline__ float bf2f(u16 h) {
  union { unsigned int u; float f; } v; v.u = ((unsigned int)h) << 16; return v.f;
}
__device__ __forceinline__ u16 f2bf(float f) {
  union { float f; unsigned int u; } v; v.f = f;
  unsigned int r = (v.u + 0x7FFFu + ((v.u >> 16) & 1u)) >> 16;
  return (u16)r;
}
__device__ __forceinline__ f32x4 mfma16(s16x8 a, s16x8 b, f32x4 c) {
  return __builtin_amdgcn_mfma_f32_16x16x32_bf16(a, b, c, 0, 0, 0);
}
// async global->LDS, 16B per lane. LDS dest = wave-uniform base + lane*16.
__device__ __forceinline__ void gld16(const void* g, void* l) {
  __builtin_amdgcn_global_load_lds((const u32_as1*)g, (u32_as3*)l, 16, 0, 0);
}

// ---------------- weight f32 -> bf16 ----------------
struct WPtrs { const float* src[12]; };

__global__ __launch_bounds__(256)
void wconv_kernel(WPtrs p, u16* __restrict__ dst) {
  int chunk = blockIdx.y;
  const float* s = p.src[chunk];
  u16* d = dst + (size_t)chunk * (kC * kC);
  int idx = (blockIdx.x * 256 + threadIdx.x) * 4;
  float4 v = *(const float4*)&s[idx];
  U16x4 o = { f2bf(v.x), f2bf(v.y), f2bf(v.z), f2bf(v.w) };
  *(U16x4*)&d[idx] = o;
}

// ---------------- LayerNorm + time-shift mix (1..4 outputs, one pass) ----------------
template<int NOUT>
__global__ __launch_bounds__(256)
void ln_mix_kernel(const float* __restrict__ x,
                   const float* __restrict__ lw, const float* __restrict__ lb,
                   const float* __restrict__ m0p, const float* __restrict__ m1p,
                   const float* __restrict__ m2p, const float* __restrict__ m3p,
                   u16* __restrict__ o0, u16* __restrict__ o1,
                   u16* __restrict__ o2, u16* __restrict__ o3)
{
  int row = blockIdx.x;
  int t = row & (kT - 1);
  int tid = threadIdx.x;
  int c0 = tid * 4;
  float4 xc = *(const float4*)&x[(size_t)row * kC + c0];
  float4 xp; xp.x = 0.f; xp.y = 0.f; xp.z = 0.f; xp.w = 0.f;
  bool hasprev = (t != 0);
  if (hasprev) xp = *(const float4*)&x[(size_t)(row - 1) * kC + c0];

  float s0 = xc.x + xc.y + xc.z + xc.w;
  float q0 = xc.x*xc.x + xc.y*xc.y + xc.z*xc.z + xc.w*xc.w;
  float s1 = xp.x + xp.y + xp.z + xp.w;
  float q1 = xp.x*xp.x + xp.y*xp.y + xp.z*xp.z + xp.w*xp.w;
  #pragma unroll
  for (int off = 1; off < 64; off <<= 1) {
    s0 += __shfl_xor(s0, off); q0 += __shfl_xor(q0, off);
    s1 += __shfl_xor(s1, off); q1 += __shfl_xor(q1, off);
  }
  __shared__ float red[16];
  int wid = tid >> 6, lane = tid & 63;
  if (lane == 0) { red[wid*4+0]=s0; red[wid*4+1]=q0; red[wid*4+2]=s1; red[wid*4+3]=q1; }
  __syncthreads();
  s0 = red[0]+red[4]+red[8]+red[12];
  q0 = red[1]+red[5]+red[9]+red[13];
  s1 = red[2]+red[6]+red[10]+red[14];
  q1 = red[3]+red[7]+red[11]+red[15];
  float mu0 = s0 * (1.f/kC), v0 = q0*(1.f/kC) - mu0*mu0, rs0 = rsqrtf(v0 + 1e-5f);
  float mu1 = s1 * (1.f/kC), v1 = q1*(1.f/kC) - mu1*mu1, rs1 = rsqrtf(v1 + 1e-5f);

  float cx[4] = { xc.x, xc.y, xc.z, xc.w };
  float px[4] = { xp.x, xp.y, xp.z, xp.w };
  U16x4 w0, w1, w2, w3;
  u16* p0 = (u16*)&w0; u16* p1 = (u16*)&w1; u16* p2 = (u16*)&w2; u16* p3 = (u16*)&w3;
  #pragma unroll
  for (int j = 0; j < 4; ++j) {
    int c = c0 + j;
    float lwc = lw[c], lbc = lb[c];
    float lnc = (cx[j] - mu0) * rs0 * lwc + lbc;
    float lnp = hasprev ? (px[j] - mu1) * rs1 * lwc + lbc : 0.f;
    float d = lnp - lnc;
    p0[j] = f2bf(lnc + d * m0p[c]);
    if (NOUT >= 2) p1[j] = f2bf(lnc + d * m1p[c]);
    if (NOUT >= 4) { p2[j] = f2bf(lnc + d * m2p[c]); p3[j] = f2bf(lnc + d * m3p[c]); }
  }
  size_t ob = (size_t)row * kC + c0;
  *(U16x4*)&o0[ob] = w0;
  if (NOUT >= 2) *(U16x4*)&o1[ob] = w1;
  if (NOUT >= 4) { *(U16x4*)&o2[ob] = w2; *(U16x4*)&o3[ob] = w3; }
}

// ---------------- 256x256 MFMA GEMM, m201-style double-barrier phases ------------
// 512 threads = 8 waves. LDS 128 KB (2 dbuf x (A 256x64 + B 256x64) bf16,
// row-halved, chunk^=(row&7) XOR swizzle). Per K-tile, 4 phases; each phase:
//   {ds_read subtile (12/4/8/0 b128, register-reuse) ; stage 1 half-tile
//    (2x gld16) ; counted vmcnt ; s_barrier ; setprio(1) 16 MFMA setprio(0) ;
//    s_barrier}.
// Stage order A0,B0,B1,A1. Ledger (steady state): outstanding 6-8; vmcnt(4)
// at P0 certifies B1(t), at P1 certifies A1(t), at P3 certifies A0,B0(t+1).
// Tail tile: vmcnt 2 -> 0. Raw s_barrier (NOT __syncthreads: must not drain
// vmcnt); "memory" fences stop LDS-load hoisting across barriers.
enum { EPI_BF16 = 0, EPI_RESID = 1, EPI_RELU2 = 2, EPI_SIGMOID = 3,
       EPI_FINAL0 = 4, EPI_FINALACC = 5 };

#define LOAD_A(mh, bfv)                                                       \
  _Pragma("unroll") for (int mf = 0; mf < 4; ++mf)                            \
    _Pragma("unroll") for (int ks = 0; ks < 2; ++ks)                          \
      Ar[mf][ks] = *(const s16x8*)&As[bfv][mh][                               \
          (wm2*64 + mf*16 + lo)*64 + 8*((ks*4 + q) ^ (lo & 7))];

#define LOAD_B(dst, nh, bfv)                                                  \
  _Pragma("unroll") for (int nf = 0; nf < 2; ++nf)                            \
    _Pragma("unroll") for (int ks = 0; ks < 2; ++ks)                          \
      dst[nf][ks] = *(const s16x8*)&Bs[bfv][nh][                              \
          (wn2*32 + nf*16 + lo)*64 + 8*((ks*4 + q) ^ (lo & 7))];

#define MFMA_Q(p, Bsrc)                                                       \
  __builtin_amdgcn_s_setprio(1);                                              \
  _Pragma("unroll") for (int mf = 0; mf < 4; ++mf)                            \
    _Pragma("unroll") for (int nf = 0; nf < 2; ++nf)                          \
      _Pragma("unroll") for (int ks = 0; ks < 2; ++ks)                        \
        acc[p][mf][nf] = mfma16(Ar[mf][ks], Bsrc[nf][ks], acc[p][mf][nf]);    \
  __builtin_amdgcn_s_setprio(0);

#define GWAIT(n) asm volatile("s_waitcnt vmcnt(" #n ")" ::: "memory")
#define BARRIER  do { __builtin_amdgcn_s_barrier();                           \
                      asm volatile("" ::: "memory"); } while (0)

template<int EPI, int LDB, int KDIM = 1024, int LDC = 1024>
__global__ __launch_bounds__(512, 2)
void gemm256(const u16* __restrict__ A, const u16* __restrict__ Wt,
             void* __restrict__ out, const float* __restrict__ resid,
             const u16* __restrict__ sigb)
{
  constexpr int NT = KDIM / 64;
  __shared__ u16 As[2][2][128 * 64];   // [dbuf][row-half][128 rows][64 k] swizzled
  __shared__ u16 Bs[2][2][128 * 64];

  const int tid = threadIdx.x;
  const int w = tid >> 6, lane = tid & 63;
  const int lo = lane & 15, q = lane >> 4;
  const int wm2 = w >> 2, wn2 = w & 3;      // 2x4 wave grid within a quadrant

  // XCD-chunked bijective swizzle (nwg % 8 == 0 for all launches here)
  const int nwg = gridDim.x * gridDim.y;
  const int orig = blockIdx.y * gridDim.x + blockIdx.x;
  const int cpx = nwg >> 3;
  const int wg = (orig & 7) * cpx + (orig >> 3);
  const int n0 = (wg % gridDim.x) * 256;
  const int m0 = (wg / gridDim.x) * 256;

  // staging geometry: per gld16, wave w covers 8 rows x 128B; lane -> (row
  // srow=lane>>3, chunk d=lane&7); source chunk pre-swizzled d ^ (row&7).
  const int srow = lane >> 3;
  const int sch  = (lane & 7) ^ srow;       // row&7 == srow (w*8, 64 are mult of 8)

  const u16* Ag = A  + (size_t)m0 * KDIM;   // A row stride == KDIM
  const u16* Bg = Wt + (size_t)n0 * LDB;

  f32x4 acc[4][4][2] = {};                  // [quadrant][mf][nf]

  auto stageA = [&](int bf, int kt, int h) {
    const u16* src = Ag + (size_t)(h*128 + w*8 + srow) * KDIM + kt*64 + 8*sch;
    u16* dst = &As[bf][h][(w*8) * 64];
    gld16(src, dst);
    gld16(src + (size_t)64 * KDIM, dst + 64*64);
  };
  auto stageB = [&](int bf, int kt, int h) {
    const u16* src = Bg + (size_t)(h*128 + w*8 + srow) * LDB + kt*64 + 8*sch;
    u16* dst = &Bs[bf][h][(w*8) * 64];
    gld16(src, dst);
    gld16(src + (size_t)64 * LDB, dst + 64*64);
  };

  // prologue: stage tile 0 (order A0,B0,B1,A1) -> 8 loads; certify A0,B0
  stageA(0, 0, 0); stageB(0, 0, 0); stageB(0, 0, 1); stageA(0, 0, 1);
  GWAIT(4);
  BARRIER;

  s16x8 Ar[4][2];                  // current A row-half frags
  s16x8 Br0[2][2], Br1[2][2];      // B col-half 0 / 1 frags (live whole K-tile)

  for (int t = 0; t < NT; ++t) {
    const int bf = t & 1, nb = bf ^ 1;
    const bool pf = (t + 1 < NT);
    // ---- P0: quadrant (0,0) ----
    LOAD_A(0, bf) LOAD_B(Br0, 0, bf)
    if (pf) { stageA(nb, t + 1, 0); GWAIT(4); } else { GWAIT(2); }  // -> B1(t)
    BARRIER;
    MFMA_Q(0, Br0)
    BARRIER;
    // ---- P1: quadrant (0,1) ----
    LOAD_B(Br1, 1, bf)
    if (pf) { stageB(nb, t + 1, 0); GWAIT(4); } else { GWAIT(0); }  // -> A1(t)
    BARRIER;
    MFMA_Q(1, Br1)
    BARRIER;
    // ---- P2: quadrant (1,1), reuse Br1 ----
    LOAD_A(1, bf)
    if (pf) stageB(nb, t + 1, 1);
    BARRIER;
    MFMA_Q(2, Br1)
    BARRIER;
    // ---- P3: quadrant (1,0), reuse Ar + Br0 ----
    if (pf) { stageA(nb, t + 1, 1); GWAIT(4); }        // -> A0,B0(t+1)
    BARRIER;
    MFMA_Q(3, Br0)
    BARRIER;
  }

  // ---- epilogue ----
  constexpr int MHq[4] = {0, 0, 1, 1}, NHq[4] = {0, 1, 1, 0};
  #pragma unroll
  for (int p = 0; p < 4; ++p) {
    #pragma unroll
    for (int mf = 0; mf < 4; ++mf) {
      #pragma unroll
      for (int nf = 0; nf < 2; ++nf) {
        #pragma unroll
        for (int rg = 0; rg < 4; ++rg) {
          int row = m0 + MHq[p]*128 + wm2*64 + mf*16 + q*4 + rg;
          int col = n0 + NHq[p]*128 + wn2*32 + nf*16 + lo;
          size_t idx = (size_t)row * LDC + col;
          float v = acc[p][mf][nf][rg];
          if (EPI == EPI_BF16) {
            ((u16*)out)[idx] = f2bf(v);
          } else if (EPI == EPI_RESID) {
            ((float*)out)[idx] = resid[idx] + v;
          } else if (EPI == EPI_RELU2) {
            float tv = v > 0.f ? v : 0.f;
            ((u16*)out)[idx] = f2bf(tv * tv);
          } else if (EPI == EPI_SIGMOID) {
            ((u16*)out)[idx] = f2bf(1.f / (1.f + __expf(-v)));
          } else if (EPI == EPI_FINAL0) {
            float s = bf2f(sigb[idx]);
            ((float*)out)[idx] = resid[idx] + s * v;
          } else { // EPI_FINALACC
            float s = bf2f(sigb[idx]);
            ((float*)out)[idx] += s * v;
          }
        }
      }
    }
  }
}

// ---------------- transpose (B,T,H,N)->(B,H,N,T), optional decay fold ----------------
template<bool DECAY>
__global__ __launch_bounds__(256)
void transpose_nt(const u16* __restrict__ src, const float* __restrict__ decay,
                  u16* __restrict__ dst)
{
  __shared__ u16 tile[64][72];
  int t0 = blockIdx.x * 64;
  int h  = blockIdx.y;
  int b  = blockIdx.z;
  int tid = threadIdx.x;
  int lrow = tid >> 3;           // 0..31
  int lcol = (tid & 7) * 8;      // 0..56
  float ed = DECAY ? __expf(decay[h]) : 0.f;

  #pragma unroll
  for (int rr = 0; rr < 2; ++rr) {
    int tr = lrow + rr * 32;
    *(uint4*)&tile[tr][lcol] =
        *(const uint4*)&src[((size_t)(b*kT + t0 + tr)) * kC + h*64 + lcol];
  }
  __syncthreads();
  #pragma unroll
  for (int rr = 0; rr < 2; ++rr) {
    int n = lrow + rr * 32;
    u16 o[8] __attribute__((aligned(16)));
    #pragma unroll
    for (int j = 0; j < 8; ++j) {
      int tglob = t0 + lcol + j;
      float v = bf2f(tile[lcol + j][n]);
      if (DECAY) v *= __expf(-ed * (float)(kQ - 1 - (tglob & (kQ - 1))));
      o[j] = f2bf(v);
    }
    *(uint4*)&dst[((size_t)((b*kH + h)*64 + n)) * kT + t0 + lcol] = *(uint4*)o;
  }
}

// ---------------- per-chunk partial state (parallel over all (b,h,c)) ----------------
__global__ __launch_bounds__(256)
void schunk_kernel(const u16* __restrict__ kTw, const u16* __restrict__ vT,
                   u16* __restrict__ SinitT)
{
  __shared__ u16 kls[64 * 136];   // 17408 B, pitch 136 (272B, 16B-aligned)
  __shared__ u16 vls[64 * 136];
  int blk = blockIdx.x;
  int c = blk & (kNC - 1), bh = blk >> 4;
  int tid = threadIdx.x, w = tid >> 6, lane = tid & 63;
  int lo = lane & 15, q = lane >> 4;
  const u16* kg = kTw + (size_t)bh * 64 * kT;
  const u16* vg = vT  + (size_t)bh * 64 * kT;
  f32x4 acc[4] = {};
  for (int half = 0; half < 2; ++half) {
    __syncthreads();
    #pragma unroll
    for (int it = 0; it < 4; ++it) {
      int row = it*16 + (tid >> 4);
      int c8  = (tid & 15) * 8;
      size_t gcol = (size_t)c * kQ + half*128 + c8;
      *(uint4*)&kls[row*136 + c8] = *(const uint4*)&kg[(size_t)row * kT + gcol];
      *(uint4*)&vls[row*136 + c8] = *(const uint4*)&vg[(size_t)row * kT + gcol];
    }
    __syncthreads();
    #pragma unroll
    for (int ks = 0; ks < 4; ++ks) {
      s16x8 av = *(const s16x8*)&vls[(w*16 + lo)*136 + ks*32 + q*8];
      #pragma unroll
      for (int nt = 0; nt < 4; ++nt) {
        s16x8 bv = *(const s16x8*)&kls[(nt*16 + lo)*136 + ks*32 + q*8];
        acc[nt] = mfma16(av, bv, acc[nt]);
      }
    }
  }
  u16* ob = SinitT + ((size_t)bh * kNC + c) * 4096;
  #pragma unroll
  for (int nt = 0; nt < 4; ++nt)
    #pragma unroll
    for (int rg = 0; rg < 4; ++rg)
      ob[(w*16 + q*4 + rg) * 64 + nt*16 + lo] = f2bf(acc[nt][rg]);
}

// decay prefix over chunk partials, in place (read slot c before overwriting).
__global__ __launch_bounds__(256)
void sscan_kernel(const float* __restrict__ decay, u16* __restrict__ SinitT)
{
  int bh = blockIdx.x;
  int h = bh & (kH - 1);
  float wQ = __expf(-__expf(decay[h]) * (float)kQ);
  u16* base = SinitT + ((size_t)bh * kNC) * 4096 + threadIdx.x * 16;
  float S[16];
  #pragma unroll
  for (int i = 0; i < 16; ++i) S[i] = 0.f;
  for (int c = 0; c < kNC; ++c) {
    u16* p = base + (size_t)c * 4096;
    u16 tmp[16] __attribute__((aligned(16)));
    *(uint4*)&tmp[0] = *(const uint4*)p;
    *(uint4*)&tmp[8] = *(const uint4*)(p + 8);
    u16 outv[16] __attribute__((aligned(16)));
    #pragma unroll
    for (int i = 0; i < 16; ++i) {
      outv[i] = f2bf(S[i]);
      S[i] = wQ * S[i] + bf2f(tmp[i]);
    }
    *(uint4*)p = *(uint4*)&outv[0];
    *(uint4*)(p + 8) = *(uint4*)&outv[8];
  }
}

// ---------------- WKV intra-chunk + GroupNorm + silu gate ----------------
__global__ __launch_bounds__(256, 3)
void wkv_y_kernel(const u16* __restrict__ r, const u16* __restrict__ k,
                  const u16* __restrict__ vT, const u16* __restrict__ SinitT,
                  const u16* __restrict__ gpre, const float* __restrict__ decay,
                  const float* __restrict__ faaaa, const float* __restrict__ gnw,
                  const float* __restrict__ gnb, u16* __restrict__ yg)
{
  __shared__ u16 kls[2][64 * 64]; // 8 KB per buf, [64 rows][64 cols] swizzled
  __shared__ u16 vls[2][64 * 64];
  __shared__ u16 pbuf[64 * 72];   // 9216 B: per-wave P strips; reused as GN-store buf
  __shared__ float wpow[kQ];      // 1 KB    (total LDS 42.25 KB)

  int blk = blockIdx.x;
  int chunk = blk & (kNC - 1), bh = blk >> 4;
  int b = bh >> 4, h = bh & (kH - 1);
  int tid = threadIdx.x, w = tid >> 6, lane = tid & 63;
  int lo = lane & 15, q = lane >> 4;
  int t0 = chunk * kQ;
  float ed = __expf(decay[h]);
  wpow[tid] = __expf(-ed * (float)tid);
  float uu = faaaa[h];

  const size_t rbase = ((size_t)(b*kT + t0)) * kC + h*64;

  const int srow = lane >> 3;                   // row within 8-row group, = row&7
  const int scol = 8 * ((lane & 7) ^ srow);     // inverse-swizzled source col (elems)
  const u16* kg0 = k  + ((size_t)(b*kT + t0)) * kC + h*64;  // rows=time, stride kC
  const u16* vg0 = vT + ((size_t)(bh*64)) * kT + t0;        // rows=n,    stride kT

  auto stage = [&](int dstbuf, int jb_) {
    const u16* kgj = kg0 + (size_t)(jb_*64) * kC;
    const u16* vgj = vg0 + jb_*64;
    #pragma unroll
    for (int it = 0; it < 2; ++it) {
      int ci  = it*4 + w;            // 8 chunks of 1 KB per strip
      int row = ci*8 + srow;
      gld16(kgj + (size_t)row * kC + scol, &kls[dstbuf][ci*512]);
      gld16(vgj + (size_t)row * kT + scol, &vls[dstbuf][ci*512]);
    }
  };

  // issue jb=0 staging first: its latency hides under r-frag loads + stateA MFMAs
  stage(0, 0);

  // ---- r A-frags once, direct from global, kept in registers ----
  s16x8 af[4][2];
  #pragma unroll
  for (int mt = 0; mt < 4; ++mt)
    #pragma unroll
    for (int ks = 0; ks < 2; ++ks)
      af[mt][ks] = *(const s16x8*)&r[rbase + (size_t)(mt*64 + w*16 + lo)*kC + ks*32 + q*8];

  f32x4 y[4][4] = {};
  // ---- step A: y = rc @ stateT^T, B-frags direct from global ----
  {
    const u16* Sg = SinitT + (size_t)blk * 4096;
    #pragma unroll
    for (int ks = 0; ks < 2; ++ks) {
      s16x8 bf[4];
      #pragma unroll
      for (int nt = 0; nt < 4; ++nt)
        bf[nt] = *(const s16x8*)&Sg[(nt*16 + lo)*64 + ks*32 + q*8];
      #pragma unroll
      for (int mt = 0; mt < 4; ++mt)
        #pragma unroll
        for (int nt = 0; nt < 4; ++nt)
          y[mt][nt] = mfma16(af[mt][ks], bf[nt], y[mt][nt]);
    }
  }
  __syncthreads();   // wpow visibility + stage(0) complete (vmcnt drained)

  // scale by wb_i = w^i
  #pragma unroll
  for (int mt = 0; mt < 4; ++mt)
    #pragma unroll
    for (int rg = 0; rg < 4; ++rg) {
      float wb = wpow[mt*64 + w*16 + q*4 + rg];
      #pragma unroll
      for (int nt = 0; nt < 4; ++nt) y[mt][nt][rg] *= wb;
    }

  // ---- intra-chunk: j-blocks of 64, double-buffered LDS, 1 barrier per jb ----
  u16* P = &pbuf[(w * 16) * 72];
  int buf = 0;
  #pragma unroll
  for (int jb = 0; jb < 4; ++jb) {
    if (jb < 3) stage(buf ^ 1, jb + 1);      // prefetch next strip-pair
    #pragma unroll
    for (int mt = jb; mt < 4; ++mt) {
      // QK^T: k B-frags from swizzled LDS
      f32x4 a[4] = {};
      #pragma unroll
      for (int ks = 0; ks < 2; ++ks)
        #pragma unroll
        for (int nt = 0; nt < 4; ++nt) {
          s16x8 kf = *(const s16x8*)&kls[buf][(nt*16 + lo)*64 + 8*((ks*4 + q) ^ (lo & 7))];
          a[nt] = mfma16(af[mt][ks], kf, a[nt]);
        }
      // mask -> P (wave-private LDS strip, pitch 72)
      #pragma unroll
      for (int nt = 0; nt < 4; ++nt)
        #pragma unroll
        for (int rg = 0; rg < 4; ++rg) {
          int i = mt*64 + w*16 + q*4 + rg;
          int j = jb*64 + nt*16 + lo;
          int d = i - j;
          float val = (d > 0) ? a[nt][rg] * wpow[d-1] : (d == 0 ? a[nt][rg] * uu : 0.f);
          P[(q*4 + rg)*72 + nt*16 + lo] = f2bf(val);
        }
      // PV: v B-frags from swizzled LDS; P A-frag from wave-private LDS
      #pragma unroll
      for (int ks = 0; ks < 2; ++ks) {
        s16x8 pf = *(const s16x8*)&P[lo*72 + ks*32 + q*8];
        #pragma unroll
        for (int nt = 0; nt < 4; ++nt) {
          s16x8 vf = *(const s16x8*)&vls[buf][(nt*16 + lo)*64 + 8*((ks*4 + q) ^ (lo & 7))];
          y[mt][nt] = mfma16(pf, vf, y[mt][nt]);
        }
      }
    }
    __syncthreads();   // prefetch landed + all waves done with buf
    buf ^= 1;
  }

  // ---- GroupNorm + silu gate, strip by strip through pbuf [64][72] ----
  float gw[4], gb[4];
  #pragma unroll
  for (int nt = 0; nt < 4; ++nt) {
    gw[nt] = gnw[h*64 + nt*16 + lo];
    gb[nt] = gnb[h*64 + nt*16 + lo];
  }
  for (int mt = 0; mt < 4; ++mt) {
    #pragma unroll
    for (int rg = 0; rg < 4; ++rg) {
      float s  = y[mt][0][rg] + y[mt][1][rg] + y[mt][2][rg] + y[mt][3][rg];
      float ss = y[mt][0][rg]*y[mt][0][rg] + y[mt][1][rg]*y[mt][1][rg]
               + y[mt][2][rg]*y[mt][2][rg] + y[mt][3][rg]*y[mt][3][rg];
      #pragma unroll
      for (int off = 1; off < 16; off <<= 1) {
        s  += __shfl_xor(s, off);
        ss += __shfl_xor(ss, off);
      }
      float mu  = s * (1.f/64.f);
      float var = ss * (1.f/64.f) - mu*mu;
      float rstd = rsqrtf(var + 6.4e-4f);   // eps = 1e-5 * 64
      #pragma unroll
      for (int nt = 0; nt < 4; ++nt) {
        float val = (y[mt][nt][rg] - mu) * rstd * gw[nt] + gb[nt];
        pbuf[(w*16 + q*4 + rg)*72 + nt*16 + lo] = f2bf(val);
      }
    }
    __syncthreads();
    #pragma unroll
    for (int it = 0; it < 2; ++it) {
      int lrow = it*32 + (tid >> 3);
      int c8  = (tid & 7) * 8;
      size_t ga = rbase + (size_t)(mt*64 + lrow)*kC + c8;
      uint2 ylo = *(const uint2*)&pbuf[lrow*72 + c8];
      uint2 yhi = *(const uint2*)&pbuf[lrow*72 + c8 + 4];
      uint4 gv = *(const uint4*)&gpre[ga];
      u16 yv[8] __attribute__((aligned(16)));
      const u16* ys = (const u16*)&ylo;
      const u16* gs = (const u16*)&gv;
      #pragma unroll
      for (int j = 0; j < 8; ++j) {
        u16 yj = (j < 4) ? ys[j] : ((const u16*)&yhi)[j-4];
        float g = bf2f(gs[j]);
        float sil = g / (1.f + __expf(-g));
        yv[j] = f2bf(bf2f(yj) * sil);
      }
      *(uint4*)&yg[ga] = *(uint4*)yv;
    }
    __syncthreads();
  }
}

// ---------------- launcher ----------------
extern "C" void kernel_launch(void* const* d_in, const int* in_sizes, int n_in,
                              void* d_out, int out_size, void* d_ws, size_t ws_size,
                              hipStream_t stream) {
  const size_t MB = 1024ull * 1024ull;
  if (ws_size < 192 * MB) return;   // graceful diagnostic fail (no OOB)

  const float* x     = (const float*)d_in[0];
  const float* ln1w  = (const float*)d_in[1];
  const float* ln1b  = (const float*)d_in[2];
  const float* tmk   = (const float*)d_in[3];
  const float* tmv   = (const float*)d_in[4];
  const float* tmr   = (const float*)d_in[5];
  const float* tmg   = (const float*)d_in[6];
  const float* decay = (const float*)d_in[7];
  const float* faaaa = (const float*)d_in[8];
  const float* Wr    = (const float*)d_in[9];
  const float* Wk    = (const float*)d_in[10];
  const float* Wv    = (const float*)d_in[11];
  const float* Wg    = (const float*)d_in[12];
  const float* Wo    = (const float*)d_in[13];
  const float* gnw   = (const float*)d_in[14];
  const float* gnb   = (const float*)d_in[15];
  const float* ln2w  = (const float*)d_in[16];
  const float* ln2b  = (const float*)d_in[17];
  const float* cmk   = (const float*)d_in[18];
  const float* cmr   = (const float*)d_in[19];
  const float* Wck   = (const float*)d_in[20];
  const float* Wcv   = (const float*)d_in[21];
  const float* Wcr   = (const float*)d_in[22];

  // lifetime-packed workspace, peak 192 MB. x1 lives in d_out (f32).
  char* ws = (char*)d_ws;
  u16*   Wb     = (u16*)(ws +   0*MB);   // [0,24)   whole run
  u16*   xr     = (u16*)(ws +  24*MB);
  u16*   xk     = (u16*)(ws +  56*MB);
  u16*   xv     = (u16*)(ws +  88*MB);
  u16*   xg     = (u16*)(ws + 120*MB);
  u16*   rb     = (u16*)(ws + 152*MB);
  u16*   kb     = (u16*)(ws +  24*MB);   // after xr dead
  u16*   vb     = (u16*)(ws +  56*MB);   // after xk dead
  u16*   gp     = (u16*)(ws +  88*MB);   // after xv dead
  u16*   vT     = (u16*)(ws + 120*MB);   // after xg dead
  u16*   kTw    = (u16*)(ws +  56*MB);   // after vb dead
  u16*   SinitT = (u16*)(ws + 184*MB);   // 8 MB
  u16*   yg     = (u16*)(ws +  56*MB);   // after kTw dead (post-schunk)
  u16*   xck    = (u16*)(ws +  24*MB);   // after kb dead (post-wkv)
  u16*   xcr    = (u16*)(ws + 152*MB);   // after rb dead (post-wkv)
  u16*   sig    = (u16*)(ws +  56*MB);   // after yg dead (post-resid)
  u16*   hbt    = (u16*)(ws +  88*MB);   // 96 MB [88,184): gp,vT,xcr dead

  const int C2 = kC * kC;
  u16* Wr_b  = Wb + 0*(size_t)C2;
  u16* Wk_b  = Wb + 1*(size_t)C2;
  u16* Wv_b  = Wb + 2*(size_t)C2;
  u16* Wg_b  = Wb + 3*(size_t)C2;
  u16* Wo_b  = Wb + 4*(size_t)C2;
  u16* Wck_b = Wb + 5*(size_t)C2;   // (3072,1024)
  u16* Wcv_b = Wb + 8*(size_t)C2;   // (1024,3072)
  u16* Wcr_b = Wb + 11*(size_t)C2;

  WPtrs wp;
  wp.src[0] = Wr;  wp.src[1] = Wk;  wp.src[2] = Wv;  wp.src[3] = Wg;  wp.src[4] = Wo;
  wp.src[5] = Wck; wp.src[6] = Wck + C2; wp.src[7] = Wck + 2*(size_t)C2;
  wp.src[8] = Wcv; wp.src[9] = Wcv + C2; wp.src[10] = Wcv + 2*(size_t)C2;
  wp.src[11] = Wcr;
  wconv_kernel<<<dim3(C2/1024, 12), 256, 0, stream>>>(wp, Wb);

  // LN1 + 4-way time-shift mix (one pass)
  ln_mix_kernel<4><<<kBT, 256, 0, stream>>>(x, ln1w, ln1b, tmr, tmk, tmv, tmg,
                                            xr, xk, xv, xg);
  // projections: 256^2 GEMM, grid 4 x 64 = 256 blocks (1/CU)
  gemm256<EPI_BF16, kC><<<dim3(4,64), 512, 0, stream>>>(xr, Wr_b, rb, nullptr, nullptr);
  gemm256<EPI_BF16, kC><<<dim3(4,64), 512, 0, stream>>>(xk, Wk_b, kb, nullptr, nullptr);
  gemm256<EPI_BF16, kC><<<dim3(4,64), 512, 0, stream>>>(xv, Wv_b, vb, nullptr, nullptr);
  gemm256<EPI_BF16, kC><<<dim3(4,64), 512, 0, stream>>>(xg, Wg_b, gp, nullptr, nullptr);

  // WKV
  transpose_nt<false><<<dim3(kT/64, kH, kB), 256, 0, stream>>>(vb, decay, vT);
  transpose_nt<true ><<<dim3(kT/64, kH, kB), 256, 0, stream>>>(kb, decay, kTw);
  schunk_kernel<<<kB*kH*kNC, 256, 0, stream>>>(kTw, vT, SinitT);
  sscan_kernel<<<kB*kH, 256, 0, stream>>>(decay, SinitT);
  wkv_y_kernel<<<kB*kH*kNC, 256, 0, stream>>>(rb, kb, vT, SinitT, gp, decay, faaaa,
                                              gnw, gnb, yg);
  // output projection + residual -> d_out (f32 residual stream lives in d_out)
  gemm256<EPI_RESID, kC><<<dim3(4,64), 512, 0, stream>>>(yg, Wo_b, d_out, x, nullptr);

  // channel mix
  ln_mix_kernel<2><<<kBT, 256, 0, stream>>>((const float*)d_out, ln2w, ln2b, cmk, cmr,
                                            nullptr, nullptr, xck, xcr, nullptr, nullptr);
  gemm256<EPI_SIGMOID, kC><<<dim3(4,64), 512, 0, stream>>>(xcr, Wcr_b, sig, nullptr, nullptr);
  // h = relu(xck @ Wck^T)^2, ONE merged N=3072 dispatch (grid 12x64 = 768 wg)
  gemm256<EPI_RELU2, kC, 1024, 3*kC><<<dim3(12,64), 512, 0, stream>>>(
      xck, Wck_b, hbt, nullptr, nullptr);
  // fused final: d_out += sig * (h @ Wcv^T), single K=3072 pass
  gemm256<EPI_FINALACC, 3*kC, 3*kC, kC><<<dim3(4,64), 512, 0, stream>>>(
      hbt, Wcv_b, (float*)d_out, nullptr, sig);
}